// Round 8
// baseline (649.556 us; speedup 1.0000x reference)
//
#include <hip/hip_runtime.h>
#include <stdint.h>

#define NN 20000      // nodes
#define NE 320000     // edges
#define NBATCH 16
#define EB_EDGES 256  // edges per tile (one block, 1024 threads, 128KB LDS, 1 block/CU)
#define EB_GRID 1250  // 1250 x 256 = 320000
#define EB_SMEM (EB_EDGES * 256 * 2 + 260 * 4)

typedef short short8 __attribute__((ext_vector_type(8)));   // 8 x bf16 bits (4 VGPR)
typedef float f32x4  __attribute__((ext_vector_type(4)));   // MFMA acc

__device__ __forceinline__ unsigned short f2bf(float f) {
  union { float f; unsigned u; } v; v.f = f;
  unsigned r = v.u + 0x7FFFu + ((v.u >> 16) & 1u);   // RNE
  return (unsigned short)(r >> 16);
}
__device__ __forceinline__ float bf2f(unsigned short h) {
  union { unsigned u; float f; } v; v.u = ((unsigned)h) << 16;
  return v.f;
}
__device__ __forceinline__ float bf2fs(short h) { return bf2f((unsigned short)h); }

// packed f32x2 -> bf16x2 (RNE), single VALU instr; src0 -> low half
__device__ __forceinline__ unsigned cvt_pk_bf16(float lo, float hi) {
  unsigned r;
  asm("v_cvt_pk_bf16_f32 %0, %1, %2" : "=v"(r) : "v"(lo), "v"(hi));
  return r;
}

// LDS tile: rows x 256 bf16, XOR-swizzled 16B granules (row stride 512B).
#define HOFF(e, k) (((e) << 8) + (((((k) >> 3) ^ ((e) & 7)) << 3) + ((k) & 7)))
// generic-K variant (row stride KT cols); KT power of two >= 64
#define HK(e, k, KT) ((e) * (KT) + (((((k) >> 3) ^ ((e) & 7)) << 3) + ((k) & 7)))

// ---------------- weight prep (+ degree histogram in blockIdx.y==13) ----------------
struct TD { const float* s; unsigned short* d; int R, C, r0, ld; };
struct TDs { TD t[13]; };

// ld==0: vectorized cast copy. ld!=0: coalesced 32x32 LDS-tile transpose
__global__ void wprep(TDs all, const int* __restrict__ dstI, int* __restrict__ deg) {
  __shared__ float tile[32][33];
  if (blockIdx.y == 13) {   // degree histogram (independent of weight prep)
    int stride = gridDim.x * blockDim.x;
    for (int e = blockIdx.x * blockDim.x + threadIdx.x; e < NE; e += stride)
      atomicAdd(&deg[dstI[e]], 1);
    return;
  }
  TD td = all.t[blockIdx.y];
  if (td.ld == 0) {                       // vector cast copy (R multiple of 8)
    int stride = gridDim.x * blockDim.x;
    int n8 = td.R >> 3;
    for (int i = blockIdx.x * blockDim.x + threadIdx.x; i < n8; i += stride) {
      const float* s = td.s + (size_t)i * 8;
      float4 lo = *(const float4*)s;
      float4 hi = *(const float4*)(s + 4);
      uint4 o = make_uint4(cvt_pk_bf16(lo.x, lo.y), cvt_pk_bf16(lo.z, lo.w),
                           cvt_pk_bf16(hi.x, hi.y), cvt_pk_bf16(hi.z, hi.w));
      *(uint4*)(td.d + (size_t)i * 8) = o;
    }
    return;
  }
  // transpose: dst[c*R + r] = src[(r0+r)*ld + c]; R,C multiples of 32
  int tilesR = td.R >> 5, tilesC = td.C >> 5;
  int nt = tilesR * tilesC;
  int tr = threadIdx.x >> 5, tc = threadIdx.x & 31;
  for (int tIdx = blockIdx.x; tIdx < nt; tIdx += gridDim.x) {
    int t_r = tIdx / tilesC, t_c = tIdx - t_r * tilesC;
    __syncthreads();   // previous iteration's reads done
#pragma unroll
    for (int rr = 0; rr < 4; ++rr) {
      int r = t_r * 32 + tr + rr * 8;
      tile[tr + rr * 8][tc] = td.s[(size_t)(td.r0 + r) * td.ld + t_c * 32 + tc];
    }
    __syncthreads();
#pragma unroll
    for (int rr = 0; rr < 4; ++rr) {
      int c = t_c * 32 + tr + rr * 8;
      td.d[(size_t)c * td.R + t_r * 32 + tc] = f2bf(tile[tc][tr + rr * 8]);
    }
  }
}

// block 0: exclusive scan of deg; blocks 1..79: batch bounds; block 80: bias concat vectors
__global__ void scan_bounds(const int* __restrict__ deg, int* __restrict__ rowstart,
                            int* __restrict__ cursor, const int* __restrict__ batch,
                            int* __restrict__ bstart,
                            const float* __restrict__ g1b1, const float* __restrict__ g2b1,
                            float* __restrict__ b1cat1, float* __restrict__ b1cat2) {
  if (blockIdx.x == 0) {
    __shared__ int part[256];
    int t = threadIdx.x;
    int c0 = t * 80; if (c0 > NN) c0 = NN;
    int c1 = c0 + 80; if (c1 > NN) c1 = NN;
    int s = 0;
    for (int i = c0; i < c1; ++i) s += deg[i];
    part[t] = s;
    __syncthreads();
    if (t == 0) {
      int run = 0;
      for (int i = 0; i < 256; ++i) { int v = part[i]; part[i] = run; run += v; }
    }
    __syncthreads();
    int run = part[t];
    for (int i = c0; i < c1; ++i) { rowstart[i] = run; cursor[i] = run; run += deg[i]; }
    if (t == 255) rowstart[NN] = run;   // == NE
  } else if (blockIdx.x == 80) {
    int t = threadIdx.x;
    b1cat1[t] = g1b1[t]; b1cat1[256 + t] = 0.f;
    b1cat2[t] = g2b1[t]; b1cat2[256 + t] = 0.f;
  } else {
    int n = (blockIdx.x - 1) * 256 + threadIdx.x;
    if (n >= NN) return;
    int bn = batch[n];
    if (n == 0) {
      for (int b2 = 0; b2 <= bn; ++b2) bstart[b2] = 0;
    } else {
      int bp = batch[n - 1];
      for (int b2 = bp + 1; b2 <= bn; ++b2) bstart[b2] = n;
    }
    if (n == NN - 1) {
      for (int b2 = bn + 1; b2 <= NBATCH; ++b2) bstart[b2] = NN;
    }
  }
}

__global__ void fillcsr(const int* __restrict__ srcI, const int* __restrict__ dstI,
                        int* __restrict__ cursor, int* __restrict__ sSrc,
                        int* __restrict__ sDst) {
  int e = blockIdx.x * 256 + threadIdx.x;
  if (e < NE) {
    int d = dstI[e];
    int slot = atomicAdd(&cursor[d], 1);
    sDst[slot] = d;
    sSrc[slot] = srcI[e];
  }
}

// ---------------- transposed-weight GEMM with LDS-staged input rows ----------------
// Out[r][f] = In[r][:] . WT[f][:] + bias; In rows staged once (kills 4x wf-redundant reads)
template <int KT>
__global__ __launch_bounds__(512, 2) void gemmTs(
    const unsigned short* __restrict__ WT, const unsigned short* __restrict__ In,
    const float* __restrict__ bias, unsigned short* __restrict__ Out,
    int M, int Nout, int ldo) {
  __shared__ __align__(16) unsigned short h[128 * KT];
  const int tid = threadIdx.x;
  const int rb0 = blockIdx.y * 128;
  {  // stage 128 In rows, coalesced
    int r = tid & 127;
    int rg = rb0 + r; if (rg >= M) rg = M - 1;
    const unsigned short* src = In + (size_t)rg * KT + (tid >> 7) * (KT / 4);
    int c0 = (tid >> 7) * (KT / 4);
#pragma unroll
    for (int i = 0; i < KT / 32; ++i) {
      short8 v = *(const short8*)(src + i * 8);
      *(short8*)&h[HK(r, c0 + i * 8, KT)] = v;
    }
  }
  __syncthreads();

  const int lane = tid & 63, w = tid >> 6;
  const int wf = w >> 1, we = w & 1;
  const int l15 = lane & 15, q = lane >> 4;
  const int fb = blockIdx.x * 256 + wf * 64;
  const int rb = rb0 + we * 64;
  f32x4 acc[4][4] = {};
  const short8 zz = {0, 0, 0, 0, 0, 0, 0, 0};
  for (int kc = 0; kc < KT; kc += 32) {
    short8 a[4], bq[4];
#pragma unroll
    for (int i = 0; i < 4; ++i) {
      if (fb + i * 16 < Nout)
        a[i] = *(const short8*)(WT + (size_t)(fb + i * 16 + l15) * KT + kc + q * 8);
      else
        a[i] = zz;
      bq[i] = *(const short8*)&h[HK(we * 64 + i * 16 + l15, kc + q * 8, KT)];
    }
#pragma unroll
    for (int i = 0; i < 4; ++i)
#pragma unroll
      for (int j = 0; j < 4; ++j)
        acc[i][j] = __builtin_amdgcn_mfma_f32_16x16x32_bf16(a[i], bq[j], acc[i][j], 0, 0, 0);
  }
#pragma unroll
  for (int i = 0; i < 4; ++i) {
    int f0 = fb + i * 16 + q * 4;
    if (f0 >= Nout) continue;
    float4 bs = make_float4(0.f, 0.f, 0.f, 0.f);
    if (bias) bs = *(const float4*)(bias + f0);
#pragma unroll
    for (int j = 0; j < 4; ++j) {
      int r = rb + j * 16 + l15;
      if (r >= M) continue;
      uint2 o = make_uint2(cvt_pk_bf16(acc[i][j][0] + bs.x, acc[i][j][1] + bs.y),
                           cvt_pk_bf16(acc[i][j][2] + bs.z, acc[i][j][3] + bs.w));
      *(uint2*)(Out + (size_t)r * ldo + f0) = o;
    }
  }
}

// ---------------- fused per-edge MLP (256-edge tiles) + dst-segmented h2 aggregation ----------------
// 1024 threads, 128KB dynamic LDS -> 1 block/CU, 16 waves (4/SIMD, 128-reg budget).
// vs 128-edge tiles: W2T L2-refetch per edge halved, barriers per edge halved,
// boundary atomics halved, occupancy 41%->50%.
__global__ __launch_bounds__(1024, 1) void edge_h2agg(
    const unsigned short* __restrict__ PQ, const int* __restrict__ sSrc,
    const int* __restrict__ sDst,
    const unsigned short* __restrict__ W2T, const float* __restrict__ b2,
    float* __restrict__ agg) {
  extern __shared__ __align__(16) char smem[];
  unsigned short* h = (unsigned short*)smem;                 // 256 x 256 bf16 = 128KB
  int* seg_s = (int*)(smem + (size_t)EB_EDGES * 256 * 2);    // [EB_EDGES]=count
  const int tid = threadIdx.x;
  const int e0 = blockIdx.x * EB_EDGES;
  if (tid == 0) seg_s[EB_EDGES] = 0;

  {  // phase 0: gather + h1 (4 threads per edge, 64 cols each)
    int r = tid & 255;
    int c0 = (tid >> 8) * 64;
    int dn = sDst[e0 + r];
    int sn = sSrc[e0 + r];
    const unsigned short* pd = PQ + (size_t)dn * 512 + c0;
    const unsigned short* ps = PQ + (size_t)sn * 512 + 256 + c0;
#pragma unroll
    for (int i = 0; i < 8; ++i) {
      short8 dv = *(const short8*)(pd + i * 8);
      short8 sv = *(const short8*)(ps + i * 8);
      float a0 = fmaxf(bf2fs(dv[0]) + bf2fs(sv[0]), 0.f);
      float a1 = fmaxf(bf2fs(dv[1]) + bf2fs(sv[1]), 0.f);
      float a2 = fmaxf(bf2fs(dv[2]) + bf2fs(sv[2]), 0.f);
      float a3 = fmaxf(bf2fs(dv[3]) + bf2fs(sv[3]), 0.f);
      float a4 = fmaxf(bf2fs(dv[4]) + bf2fs(sv[4]), 0.f);
      float a5 = fmaxf(bf2fs(dv[5]) + bf2fs(sv[5]), 0.f);
      float a6 = fmaxf(bf2fs(dv[6]) + bf2fs(sv[6]), 0.f);
      float a7 = fmaxf(bf2fs(dv[7]) + bf2fs(sv[7]), 0.f);
      uint4 o = make_uint4(cvt_pk_bf16(a0, a1), cvt_pk_bf16(a2, a3),
                           cvt_pk_bf16(a4, a5), cvt_pk_bf16(a6, a7));
      *(uint4*)&h[HOFF(r, c0 + i * 8)] = o;
    }
  }
  __syncthreads();

  const int lane = tid & 63, w = tid >> 6;
  const int wf = w >> 2, we = w & 3;     // 4 feat-blocks x 4 edge-blocks of 64
  const int l15 = lane & 15, q = lane >> 4;
  const int fb = wf * 64, eb = we * 64;
  f32x4 acc[4][4];

  // ---- GEMM: h2^T = W2T @ h1^T ----
#pragma unroll
  for (int i = 0; i < 4; ++i)
#pragma unroll
    for (int j = 0; j < 4; ++j) { f32x4 z = {0.f, 0.f, 0.f, 0.f}; acc[i][j] = z; }
  for (int kc = 0; kc < 256; kc += 32) {
    short8 a[4], bq[4];
#pragma unroll
    for (int i = 0; i < 4; ++i)
      a[i] = *(const short8*)(W2T + (size_t)(fb + i * 16 + l15) * 256 + kc + q * 8);
#pragma unroll
    for (int j = 0; j < 4; ++j)
      bq[j] = *(const short8*)&h[HOFF(eb + j * 16 + l15, kc + q * 8)];
#pragma unroll
    for (int i = 0; i < 4; ++i)
#pragma unroll
      for (int j = 0; j < 4; ++j)
        acc[i][j] = __builtin_amdgcn_mfma_f32_16x16x32_bf16(a[i], bq[j], acc[i][j], 0, 0, 0);
  }
  __syncthreads();  // all reads of h1 done
#pragma unroll
  for (int i = 0; i < 4; ++i) {
    int f0 = fb + i * 16 + q * 4;
    float4 bs = *(const float4*)(b2 + f0);
#pragma unroll
    for (int j = 0; j < 4; ++j) {
      int e = eb + j * 16 + l15;
      float v0 = fmaxf(acc[i][j][0] + bs.x, 0.f);
      float v1 = fmaxf(acc[i][j][1] + bs.y, 0.f);
      float v2 = fmaxf(acc[i][j][2] + bs.z, 0.f);
      float v3 = fmaxf(acc[i][j][3] + bs.w, 0.f);
      uint2 o = make_uint2(cvt_pk_bf16(v0, v1), cvt_pk_bf16(v2, v3));
      *(uint2*)&h[HOFF(e, f0)] = o;  // h2
    }
  }
  if (tid < EB_EDGES) {
    int d0 = sDst[e0 + tid];
    bool flag = (tid == 0) || (sDst[e0 + tid - 1] != d0);
    if (flag) {
      int idx = atomicAdd(&seg_s[EB_EDGES], 1);
      seg_s[idx] = tid;
    }
  }
  __syncthreads();

  // segmented reduction of h2: 16 groups x 64 lanes (4 feats/lane), fp32
  {
    int cnt = seg_s[EB_EDGES];
    int f4 = (tid & 63) * 4;
    int sg = tid >> 6;
    for (int k = sg; k < cnt; k += 16) {
      int start = seg_s[k];
      int end = EB_EDGES;
      for (int j2 = 0; j2 < cnt; ++j2) {
        int v = seg_s[j2];
        if (v > start && v < end) end = v;
      }
      int node = sDst[e0 + start];
      float s0 = 0.f, s1 = 0.f, s2 = 0.f, s3 = 0.f;
      for (int rr = start; rr < end; ++rr) {
        ushort4 v = *(const ushort4*)&h[HOFF(rr, f4)];
        s0 += bf2f(v.x); s1 += bf2f(v.y); s2 += bf2f(v.z); s3 += bf2f(v.w);
      }
      float* pr = agg + (size_t)node * 256 + f4;
      if (start == 0 || end == EB_EDGES) {  // run may continue in neighbor tile
        atomicAdd(pr + 0, s0); atomicAdd(pr + 1, s1);
        atomicAdd(pr + 2, s2); atomicAdd(pr + 3, s3);
      } else {                              // wholly inside this tile: unique owner
        *(float4*)pr = make_float4(s0, s1, s2, s3);
      }
    }
  }
}

// ---------------- per-node GEMM fused with relu+LN: out = LN(relu(agg@W3 + deg*b3)) -------------
__global__ __launch_bounds__(512, 2) void node_gemm_ln(
    const unsigned short* __restrict__ W3T, const float* __restrict__ aggH2,
    const float* __restrict__ b3, const int* __restrict__ deg,
    const float* __restrict__ lng, const float* __restrict__ lnb,
    unsigned short* __restrict__ out) {
  __shared__ __align__(16) unsigned short h[128 * 256];  // 64 KB
  __shared__ float rstat[256];   // [0..127]=sum, [128..255]=sumsq per local row
  const int tid = threadIdx.x;
  const int rb0 = blockIdx.x * 128;
  if (tid < 256) rstat[tid] = 0.f;
  {  // stage 128 rows, convert fp32 -> bf16 once
    int r = tid & 127;
    int rg = rb0 + r; if (rg >= NN) rg = NN - 1;
    int c0 = (tid >> 7) * 64;
    const float* src = aggH2 + (size_t)rg * 256 + c0;
#pragma unroll
    for (int i = 0; i < 8; ++i) {
      float4 lo = *(const float4*)(src + i * 8);
      float4 hi = *(const float4*)(src + i * 8 + 4);
      uint4 o = make_uint4(cvt_pk_bf16(lo.x, lo.y), cvt_pk_bf16(lo.z, lo.w),
                           cvt_pk_bf16(hi.x, hi.y), cvt_pk_bf16(hi.z, hi.w));
      *(uint4*)&h[HOFF(r, c0 + i * 8)] = o;
    }
  }
  __syncthreads();

  const int lane = tid & 63, w = tid >> 6;
  const int wf = w >> 1, we = w & 1;
  const int l15 = lane & 15, q = lane >> 4;
  const int fb = wf * 64;                      // 256 feats per block via 4 wave-pairs
  const int rb = rb0 + we * 64;                // 128 rows per block via 2 halves
  f32x4 acc[4][4] = {};
  for (int kc = 0; kc < 256; kc += 32) {
    short8 a[4], bq[4];
#pragma unroll
    for (int i = 0; i < 4; ++i) {
      a[i] = *(const short8*)(W3T + (size_t)(fb + i * 16 + l15) * 256 + kc + q * 8);
      bq[i] = *(const short8*)&h[HOFF(we * 64 + i * 16 + l15, kc + q * 8)];
    }
#pragma unroll
    for (int i = 0; i < 4; ++i)
#pragma unroll
      for (int j = 0; j < 4; ++j)
        acc[i][j] = __builtin_amdgcn_mfma_f32_16x16x32_bf16(a[i], bq[j], acc[i][j], 0, 0, 0);
  }

  // per-row deg and bias fragments
  float dgj[4];
#pragma unroll
  for (int j = 0; j < 4; ++j) {
    int rr = rb + j * 16 + l15;
    dgj[j] = (float)deg[rr < NN ? rr : NN - 1];
  }
  f32x4 bsv[4];
#pragma unroll
  for (int i = 0; i < 4; ++i)
    bsv[i] = *(const f32x4*)(b3 + fb + i * 16 + q * 4);

  // pass 1: stats.  v = relu(acc + dg*b3); reduce 64 feats via shfl over q-lanes,
  // then LDS atomicAdd across the 4 wf wave-pairs.
#pragma unroll
  for (int j = 0; j < 4; ++j) {
    float s = 0.f, sq = 0.f;
#pragma unroll
    for (int i = 0; i < 4; ++i)
#pragma unroll
      for (int r = 0; r < 4; ++r) {
        float v = fmaxf(acc[i][j][r] + dgj[j] * bsv[i][r], 0.f);
        s += v; sq += v * v;
      }
    s += __shfl_xor(s, 16); s += __shfl_xor(s, 32);
    sq += __shfl_xor(sq, 16); sq += __shfl_xor(sq, 32);
    if (q == 0) {
      int lr = we * 64 + j * 16 + l15;
      atomicAdd(&rstat[lr], s);
      atomicAdd(&rstat[128 + lr], sq);
    }
  }
  __syncthreads();

  // pass 2: normalize from live accumulators, write bf16
#pragma unroll
  for (int j = 0; j < 4; ++j) {
    int lr = we * 64 + j * 16 + l15;
    int rr = rb + j * 16 + l15;
    float mu = rstat[lr] * (1.f / 256.f);
    float var = rstat[128 + lr] * (1.f / 256.f) - mu * mu;
    float rs = rsqrtf(var + 1e-5f);
    if (rr < NN) {
#pragma unroll
      for (int i = 0; i < 4; ++i) {
        int f0 = fb + i * 16 + q * 4;
        f32x4 gg = *(const f32x4*)(lng + f0);
        f32x4 bb = *(const f32x4*)(lnb + f0);
        float o0 = (fmaxf(acc[i][j][0] + dgj[j] * bsv[i][0], 0.f) - mu) * rs * gg[0] + bb[0];
        float o1 = (fmaxf(acc[i][j][1] + dgj[j] * bsv[i][1], 0.f) - mu) * rs * gg[1] + bb[1];
        float o2 = (fmaxf(acc[i][j][2] + dgj[j] * bsv[i][2], 0.f) - mu) * rs * gg[2] + bb[2];
        float o3 = (fmaxf(acc[i][j][3] + dgj[j] * bsv[i][3], 0.f) - mu) * rs * gg[3] + bb[3];
        *(uint2*)(out + (size_t)rr * 256 + f0) =
            make_uint2(cvt_pk_bf16(o0, o1), cvt_pk_bf16(o2, o3));
      }
    }
  }
}

// ---------------- fused assignment MLP + gumbel softmax (64 node-rows per block) ----------------
__global__ __launch_bounds__(512, 4) void assign_gumbel(
    const unsigned short* __restrict__ x2b, const unsigned short* __restrict__ aw1T,
    const float* __restrict__ ab1, const unsigned short* __restrict__ aw2T,
    const float* __restrict__ ab2, const float* __restrict__ u,
    float* __restrict__ sf, float* __restrict__ entacc, float* __restrict__ avgacc) {
  __shared__ __align__(16) unsigned short sh[64 * 256];   // 32 KB
  __shared__ float sh_logit[64 * 33];
  __shared__ float lavg[32];
  __shared__ float lent;
  const int tid = threadIdx.x;
  const int n0 = blockIdx.x * 64;
  if (tid < 32) lavg[tid] = 0.f;
  if (tid == 0) lent = 0.f;

  const int lane = tid & 63, w = tid >> 6;
  const int l15 = lane & 15, q = lane >> 4;

  {  // phase A: assh tile
    const int wf = w >> 1, we = w & 1;
    const int fb = wf * 64, eb = we * 32;
    f32x4 acc[4][2];
#pragma unroll
    for (int i = 0; i < 4; ++i)
#pragma unroll
      for (int j = 0; j < 2; ++j) { f32x4 z = {0.f, 0.f, 0.f, 0.f}; acc[i][j] = z; }
    for (int kc = 0; kc < 256; kc += 32) {
      short8 a[4], bq[2];
#pragma unroll
      for (int i = 0; i < 4; ++i)
        a[i] = *(const short8*)(aw1T + (size_t)(fb + i * 16 + l15) * 256 + kc + q * 8);
#pragma unroll
      for (int j = 0; j < 2; ++j) {
        int rr = n0 + eb + j * 16 + l15;
        if (rr >= NN) rr = NN - 1;
        bq[j] = *(const short8*)(x2b + (size_t)rr * 256 + kc + q * 8);
      }
#pragma unroll
      for (int i = 0; i < 4; ++i)
#pragma unroll
        for (int j = 0; j < 2; ++j)
          acc[i][j] = __builtin_amdgcn_mfma_f32_16x16x32_bf16(a[i], bq[j], acc[i][j], 0, 0, 0);
    }
#pragma unroll
    for (int i = 0; i < 4; ++i) {
      int f0 = fb + i * 16 + q * 4;
      float4 bs = *(const float4*)(ab1 + f0);
#pragma unroll
      for (int j = 0; j < 2; ++j) {
        int e = eb + j * 16 + l15;
        ushort4 o;
        o.x = f2bf(fmaxf(acc[i][j][0] + bs.x, 0.f));
        o.y = f2bf(fmaxf(acc[i][j][1] + bs.y, 0.f));
        o.z = f2bf(fmaxf(acc[i][j][2] + bs.z, 0.f));
        o.w = f2bf(fmaxf(acc[i][j][3] + bs.w, 0.f));
        *(ushort4*)&sh[HOFF(e, f0)] = o;
      }
    }
  }
  __syncthreads();

  {  // phase B: logits (N=32). wave w: row-group rg=w&3, feat-group fg=w>>2 (fg<2)
    const int rg = w & 3, fg = w >> 2;
    if (fg < 2) {
      f32x4 acc = {0.f, 0.f, 0.f, 0.f};
      for (int kc = 0; kc < 256; kc += 32) {
        short8 a = *(const short8*)(aw2T + (size_t)(fg * 16 + l15) * 256 + kc + q * 8);
        short8 bq = *(const short8*)&sh[HOFF(rg * 16 + l15, kc + q * 8)];
        acc = __builtin_amdgcn_mfma_f32_16x16x32_bf16(a, bq, acc, 0, 0, 0);
      }
      int rowL = rg * 16 + l15;
#pragma unroll
      for (int t2 = 0; t2 < 4; ++t2) {
        int f = fg * 16 + q * 4 + t2;
        sh_logit[rowL * 33 + f] = acc[t2] + ab2[f];
      }
    }
  }
  __syncthreads();

  // phase C: gumbel softmax, 4 threads per row (8 slots each)
  if (tid < 256) {
    int rowL = tid >> 2, sub = tid & 3;
    int n = n0 + rowL;
    if (n < NN) {
      int j0 = sub * 8;
      float z[8];
      float4 u0 = *(const float4*)(u + (size_t)n * 32 + j0);
      float4 u1 = *(const float4*)(u + (size_t)n * 32 + j0 + 4);
      float uu[8] = {u0.x, u0.y, u0.z, u0.w, u1.x, u1.y, u1.z, u1.w};
      float m = -1e30f;
#pragma unroll
      for (int j = 0; j < 8; ++j) {
        z[j] = sh_logit[rowL * 33 + j0 + j] - logf(-logf(uu[j] + 1e-9f) + 1e-9f);
        m = fmaxf(m, z[j]);
      }
      m = fmaxf(m, __shfl_xor(m, 1));
      m = fmaxf(m, __shfl_xor(m, 2));
      float sum = 0.f;
#pragma unroll
      for (int j = 0; j < 8; ++j) { z[j] = expf(z[j] - m); sum += z[j]; }
      sum += __shfl_xor(sum, 1);
      sum += __shfl_xor(sum, 2);
      float inv = 1.f / sum;
      float ent = 0.f;
      float so[8];
#pragma unroll
      for (int j = 0; j < 8; ++j) {
        float sj = z[j] * inv;
        so[j] = sj;
        ent += sj * logf(sj + 1e-9f);
        atomicAdd(&lavg[j0 + j], sj);
      }
      *(float4*)(sf + (size_t)n * 32 + j0) = make_float4(so[0], so[1], so[2], so[3]);
      *(float4*)(sf + (size_t)n * 32 + j0 + 4) = make_float4(so[4], so[5], so[6], so[7]);
      ent += __shfl_xor(ent, 1);
      ent += __shfl_xor(ent, 2);
      if (sub == 0) atomicAdd(&lent, ent);
    }
  }
  __syncthreads();
  if (tid < 32) atomicAdd(&avgacc[tid], lavg[tid]);
  if (tid == 0) atomicAdd(entacc, lent);
}

// ---------------- pooling stage 1: per-(batch, chunk-set) partials, atomic-free ----------------
__global__ __launch_bounds__(512, 4) void pool_part(
    const unsigned short* __restrict__ x2b, const float* __restrict__ sf,
    const int* __restrict__ bstart, float* __restrict__ part) {
  const int b = blockIdx.x, ci = blockIdx.y;
  const int n0b = bstart[b], n1b = bstart[b + 1];
  const int t = threadIdx.x;
  const int si = t >> 4;            // 0..31
  const int h0 = (t & 15) * 16;     // 0..240
  float acc[16];
#pragma unroll
  for (int k = 0; k < 16; ++k) acc[k] = 0.f;
  for (int nst = n0b + ci * 64; nst < n1b; nst += 16 * 64) {
    int nend = (nst + 64 < n1b) ? nst + 64 : n1b;
    for (int n = nst; n < nend; ++n) {
      float sv = sf[(size_t)n * 32 + si];
      const unsigned short* xr = x2b + (size_t)n * 256 + h0;
      short8 x0 = *(const short8*)xr;
      short8 x1 = *(const short8*)(xr + 8);
#pragma unroll
      for (int j = 0; j < 8; ++j) acc[j] = fmaf(sv, bf2fs(x0[j]), acc[j]);
#pragma unroll
      for (int j = 0; j < 8; ++j) acc[8 + j] = fmaf(sv, bf2fs(x1[j]), acc[8 + j]);
    }
  }
  float* pp = part + (((size_t)b * 16 + ci) << 13) + si * 256 + h0;
#pragma unroll
  for (int k = 0; k < 16; k += 4)
    *(float4*)(pp + k) = make_float4(acc[k], acc[k + 1], acc[k + 2], acc[k + 3]);
}

// ---------------- pooling stage 2: pooled[b][si][h] = sum_ci part[b][ci][si][h] ----------------
__global__ void pool_reduce(const float* __restrict__ part, float* __restrict__ pooled) {
  int g = blockIdx.x * 256 + threadIdx.x;   // 512 blocks x 256 = 131072 outputs
  int b = g >> 13, rem = g & 8191;
  const float* p = part + (((size_t)b * 16) << 13) + rem;
  float s = 0.f;
#pragma unroll
  for (int c = 0; c < 16; ++c) s += p[(size_t)c << 13];
  pooled[g] = s;
}

// ---------------- fused output MLP (+ loss in block 0): latent = relu(pooled@ow1+ob1)@ow2+ob2 ----
__global__ __launch_bounds__(512, 4) void out_mlp(
    const float* __restrict__ pooled, const unsigned short* __restrict__ ow1T,
    const float* __restrict__ ob1, const unsigned short* __restrict__ ow2T,
    const float* __restrict__ ob2, float* __restrict__ latent,
    const float* __restrict__ accs, float* __restrict__ outloss) {
  __shared__ __align__(16) unsigned short sh[64 * 256];   // hid tile, 32 KB
  const int tid = threadIdx.x;
  const int n0 = blockIdx.x * 64;
  const int lane = tid & 63, w = tid >> 6;
  const int l15 = lane & 15, q = lane >> 4;

  if (blockIdx.x == 0 && tid < 64) {  // loss (accs ready: assign_gumbel completed earlier)
    float d = 0.f;
    if (tid < 32) {
      float a = accs[16 + tid] * (1.f / NN);
      d = a * logf(a + 1e-9f);
    }
    for (int off = 32; off >= 1; off >>= 1) d += __shfl_xor(d, off);
    if (tid == 0) outloss[0] = -accs[0] * (1.f / NN) + d;
  }

  {  // phase A: hid = relu(pooled @ ow1 + ob1), pooled converted inline to bf16
    const int wf = w >> 1, we = w & 1;
    const int fb = wf * 64, eb = we * 32;
    f32x4 acc[4][2];
#pragma unroll
    for (int i = 0; i < 4; ++i)
#pragma unroll
      for (int j = 0; j < 2; ++j) { f32x4 z = {0.f, 0.f, 0.f, 0.f}; acc[i][j] = z; }
    for (int kc = 0; kc < 256; kc += 32) {
      short8 a[4], bq[2];
#pragma unroll
      for (int i = 0; i < 4; ++i)
        a[i] = *(const short8*)(ow1T + (size_t)(fb + i * 16 + l15) * 256 + kc + q * 8);
#pragma unroll
      for (int j = 0; j < 2; ++j) {
        int rr = n0 + eb + j * 16 + l15;
        const float* pr = pooled + (size_t)rr * 256 + kc + q * 8;
        float4 lo = *(const float4*)pr;
        float4 hi = *(const float4*)(pr + 4);
        short8 o;
        o[0] = (short)f2bf(lo.x); o[1] = (short)f2bf(lo.y);
        o[2] = (short)f2bf(lo.z); o[3] = (short)f2bf(lo.w);
        o[4] = (short)f2bf(hi.x); o[5] = (short)f2bf(hi.y);
        o[6] = (short)f2bf(hi.z); o[7] = (short)f2bf(hi.w);
        bq[j] = o;
      }
#pragma unroll
      for (int i = 0; i < 4; ++i)
#pragma unroll
        for (int j = 0; j < 2; ++j)
          acc[i][j] = __builtin_amdgcn_mfma_f32_16x16x32_bf16(a[i], bq[j], acc[i][j], 0, 0, 0);
    }
#pragma unroll
    for (int i = 0; i < 4; ++i) {
      int f0 = fb + i * 16 + q * 4;
      float4 bs = *(const float4*)(ob1 + f0);
#pragma unroll
      for (int j = 0; j < 2; ++j) {
        int e = eb + j * 16 + l15;
        ushort4 o;
        o.x = f2bf(fmaxf(acc[i][j][0] + bs.x, 0.f));
        o.y = f2bf(fmaxf(acc[i][j][1] + bs.y, 0.f));
        o.z = f2bf(fmaxf(acc[i][j][2] + bs.z, 0.f));
        o.w = f2bf(fmaxf(acc[i][j][3] + bs.w, 0.f));
        *(ushort4*)&sh[HOFF(e, f0)] = o;
      }
    }
  }
  __syncthreads();

  {  // phase B: latent = hid @ ow2 + ob2 (Nout=128)
    const int wf = w >> 1, we = w & 1;
    const int fb = wf * 32, eb = we * 32;
    f32x4 acc[2][2];
#pragma unroll
    for (int i = 0; i < 2; ++i)
#pragma unroll
      for (int j = 0; j < 2; ++j) { f32x4 z = {0.f, 0.f, 0.f, 0.f}; acc[i][j] = z; }
    for (int kc = 0; kc < 256; kc += 32) {
      short8 a[2], bq[2];
#pragma unroll
      for (int i = 0; i < 2; ++i)
        a[i] = *(const short8*)(ow2T + (size_t)(fb + i * 16 + l15) * 256 + kc + q * 8);
#pragma unroll
      for (int j = 0; j < 2; ++j)
        bq[j] = *(const short8*)&sh[HOFF(eb + j * 16 + l15, kc + q * 8)];
#pragma unroll
      for (int i = 0; i < 2; ++i)
#pragma unroll
        for (int j = 0; j < 2; ++j)
          acc[i][j] = __builtin_amdgcn_mfma_f32_16x16x32_bf16(a[i], bq[j], acc[i][j], 0, 0, 0);
    }
#pragma unroll
    for (int i = 0; i < 2; ++i) {
      int f0 = fb + i * 16 + q * 4;
      float4 bs = *(const float4*)(ob2 + f0);
#pragma unroll
      for (int j = 0; j < 2; ++j) {
        int rr = n0 + eb + j * 16 + l15;
        *(float4*)(latent + (size_t)rr * 128 + f0) =
            make_float4(acc[i][j][0] + bs.x, acc[i][j][1] + bs.y,
                        acc[i][j][2] + bs.z, acc[i][j][3] + bs.w);
      }
    }
  }
}

// ---------------- orchestration ----------------
extern "C" void kernel_launch(void* const* d_in, const int* in_sizes, int n_in,
                              void* d_out, int out_size, void* d_ws, size_t ws_size,
                              hipStream_t stream) {
  (void)in_sizes; (void)n_in; (void)out_size; (void)ws_size;
  const float* x = (const float*)d_in[0];
  const float* u = (const float*)d_in[1];
  const int* ei = (const int*)d_in[2];
  const int* batch = (const int*)d_in[3];
  const float* g1w1 = (const float*)d_in[4];
  const float* g1b1 = (const float*)d_in[5];
  const float* g1w2 = (const float*)d_in[6];
  const float* g1b2 = (const float*)d_in[7];
  const float* g1w3 = (const float*)d_in[8];
  const float* g1b3 = (const float*)d_in[9];
  const float* ln1g = (const float*)d_in[10];
  const float* ln1b = (const float*)d_in[11];
  const float* g2w1 = (const float*)d_in[12];
  const float* g2b1 = (const float*)d_in[13];
  const float* g2w2 = (const float*)d_in[14];
  const float* g2b2 = (const float*)d_in[15];
  const float* g2w3 = (const float*)d_in[16];
  const float* g2b3 = (const float*)d_in[17];
  const float* ln2g = (const float*)d_in[18];
  const float* ln2b = (const float*)d_in[19];
  const float* aw1 = (const float*)d_in[20];
  const float* ab1 = (const float*)d_in[21];
  const float* aw2 = (const float*)d_in[22];
  const float* ab2 = (const float*)d_in[23];
  const float* ow1 = (const float*)d_in[24];
  const float* ob1 = (const float*)d_in[25];
  const float* ow2 = (const float*)d_in[26];
  const float* ob2 = (const float*)d_in[27];
  const int* srcI = ei;        // edge_index[0] = src
  const int* dstI = ei + NE;   // edge_index[1] = dst

  char* wp = (char*)d_ws;
  size_t off = 0;
  auto alloc = [&](size_t bytes) {
    void* p = wp + off;
    off += (bytes + 255) & ~(size_t)255;
    return p;
  };
  unsigned short* W1catT = (unsigned short*)alloc((size_t)512 * 64 * 2);
  unsigned short* W2catT = (unsigned short*)alloc((size_t)512 * 256 * 2);
  unsigned short* g1w2T = (unsigned short*)alloc((size_t)256 * 256 * 2);
  unsigned short* g1w3T = (unsigned short*)alloc((size_t)256 * 256 * 2);
  unsigned short* g2w2T = (unsigned short*)alloc((size_t)256 * 256 * 2);
  unsigned short* g2w3T = (unsigned short*)alloc((size_t)256 * 256 * 2);
  unsigned short* aw1T = (unsigned short*)alloc((size_t)256 * 256 * 2);
  unsigned short* aw2T = (unsigned short*)alloc((size_t)32 * 256 * 2);
  unsigned short* ow1T = (unsigned short*)alloc((size_t)256 * 256 * 2);
  unsigned short* ow2T = (unsigned short*)alloc((size_t)128 * 256 * 2);
  unsigned short* xb = (unsigned short*)alloc((size_t)NN * 64 * 2);
  unsigned short* PQ = (unsigned short*)alloc((size_t)NN * 512 * 2);
  unsigned short* x1b = (unsigned short*)alloc((size_t)NN * 256 * 2);
  unsigned short* x2b = (unsigned short*)alloc((size_t)NN * 256 * 2);
  int* bstart = (int*)alloc(32 * 4);
  int* cursor = (int*)alloc((size_t)NN * 4);
  int* rowstart = (int*)alloc((size_t)(NN + 1) * 4);
  int* sSrc = (int*)alloc((size_t)NE * 4);
  int* sDst = (int*)alloc((size_t)NE * 4);
  float* b1cat1 = (float*)alloc(512 * 4);
  float* b1cat2 = (float*)alloc(512 * 4);
  // ---- contiguous zero-init region (single memset) ----
  char* zbase = (char*)(wp + off);
  float* accs = (float*)alloc(64 * 4);
  float* pooled = (float*)alloc((size_t)512 * 256 * 4);
  int* deg = (int*)alloc((size_t)NN * 4);
  float* agg1 = (float*)alloc((size_t)NN * 256 * 4);
  float* agg2 = (float*)alloc((size_t)NN * 256 * 4);
  size_t zbytes = (size_t)((char*)(wp + off) - zbase);

  // pool partials (16*16*8192 fp32 = 8.4 MB) reuse agg1: agg1 is dead after layer-1 node_gemm_ln.
  float* poolpart = agg1;

  float* out_f = (float*)d_out;
  float* out_latent = out_f;                 // [16*32*128] = 65536
  float* out_s = out_f + 65536;              // [20000*32]
  float* out_loss = out_f + 65536 + 640000;  // [1]

  TDs tds;
  tds.t[0] = {g1w1, W1catT, 64, 256, 0, 256};
  tds.t[1] = {g1w1, W1catT + 256 * 64, 64, 256, 64, 256};
  tds.t[2] = {g1w2, g1w2T, 256, 256, 0, 256};
  tds.t[3] = {g1w3, g1w3T, 256, 256, 0, 256};
  tds.t[4] = {g2w1, W2catT, 256, 256, 0, 256};
  tds.t[5] = {g2w1, W2catT + 256 * 256, 256, 256, 256, 256};
  tds.t[6] = {g2w2, g2w2T, 256, 256, 0, 256};
  tds.t[7] = {g2w3, g2w3T, 256, 256, 0, 256};
  tds.t[8] = {aw1, aw1T, 256, 256, 0, 256};
  tds.t[9] = {aw2, aw2T, 256, 32, 0, 32};
  tds.t[10] = {ow1, ow1T, 256, 256, 0, 256};
  tds.t[11] = {ow2, ow2T, 256, 128, 0, 128};
  tds.t[12] = {x, xb, NN * 64, 1, 0, 0};

  // allow 128KB+ dynamic LDS for the edge kernel (one-time, immediate host call)
  static int attr_set = 0;
  if (!attr_set) {
    (void)hipFuncSetAttribute((const void*)edge_h2agg,
                              hipFuncAttributeMaxDynamicSharedMemorySize, EB_SMEM);
    attr_set = 1;
  }

  (void)hipMemsetAsync(zbase, 0, zbytes, stream);   // accs+pooled+deg+agg1+agg2
  // weight prep + degree histogram in one dispatch (y==13 -> hist)
  wprep<<<dim3(128, 14), 256, 0, stream>>>(tds, dstI, deg);

  // CSR scan + batch bounds + bias concat, then permutation fill
  scan_bounds<<<dim3(81), 256, 0, stream>>>(deg, rowstart, cursor, batch, bstart,
                                            g1b1, g2b1, b1cat1, b1cat2);
  fillcsr<<<dim3(1250), 256, 0, stream>>>(srcI, dstI, cursor, sSrc, sDst);

  // layer 1 (b1 folded into PQ dst half; W3+b3+relu+LN fused into node_gemm_ln)
  gemmTs<64><<<dim3(2, 157), 512, 0, stream>>>(W1catT, xb, b1cat1, PQ, NN, 512, 512);
  edge_h2agg<<<dim3(EB_GRID), 1024, EB_SMEM, stream>>>(PQ, sSrc, sDst, g1w2T, g1b2, agg1);
  node_gemm_ln<<<dim3(157), 512, 0, stream>>>(g1w3T, agg1, g1b3, deg, ln1g, ln1b, x1b);

  // layer 2
  gemmTs<256><<<dim3(2, 157), 512, 0, stream>>>(W2catT, x1b, b1cat2, PQ, NN, 512, 512);
  edge_h2agg<<<dim3(EB_GRID), 1024, EB_SMEM, stream>>>(PQ, sSrc, sDst, g2w2T, g2b2, agg2);
  node_gemm_ln<<<dim3(157), 512, 0, stream>>>(g2w3T, agg2, g2b3, deg, ln2g, ln2b, x2b);

  // fused assignment MLP + gumbel softmax (s fp32 to d_out)
  assign_gumbel<<<dim3(313), 512, 0, stream>>>(x2b, aw1T, ab1, aw2T, ab2, u,
                                               out_s, accs, accs + 16);

  // pooling: atomic-free two-stage (partials reuse agg1, dead after layer-1 node_gemm_ln)
  pool_part<<<dim3(16, 16), 512, 0, stream>>>(x2b, out_s, bstart, poolpart);
  pool_reduce<<<dim3(512), 256, 0, stream>>>(poolpart, pooled);

  // fused output MLP (+loss)
  out_mlp<<<dim3(8), 512, 0, stream>>>(pooled, ow1T, ob1, ow2T, ob2, out_latent,
                                       accs, out_loss);
}

// Round 9
// 638.164 us; speedup vs baseline: 1.0179x; 1.0179x over previous
//
#include <hip/hip_runtime.h>
#include <stdint.h>

#define NN 20000      // nodes
#define NE 320000     // edges
#define NBATCH 16
#define NTILE 2500    // 128-edge tiles

typedef short short8 __attribute__((ext_vector_type(8)));   // 8 x bf16 bits (4 VGPR)
typedef float f32x4  __attribute__((ext_vector_type(4)));   // MFMA acc

__device__ __forceinline__ unsigned short f2bf(float f) {
  union { float f; unsigned u; } v; v.f = f;
  unsigned r = v.u + 0x7FFFu + ((v.u >> 16) & 1u);   // RNE
  return (unsigned short)(r >> 16);
}
__device__ __forceinline__ float bf2f(unsigned short h) {
  union { unsigned u; float f; } v; v.u = ((unsigned)h) << 16;
  return v.f;
}
__device__ __forceinline__ float bf2fs(short h) { return bf2f((unsigned short)h); }

// packed f32x2 -> bf16x2 (RNE), single VALU instr; src0 -> low half
__device__ __forceinline__ unsigned cvt_pk_bf16(float lo, float hi) {
  unsigned r;
  asm("v_cvt_pk_bf16_f32 %0, %1, %2" : "=v"(r) : "v"(lo), "v"(hi));
  return r;
}

// LDS tile: rows x 256 bf16, XOR-swizzled 16B granules (row stride 512B).
#define HOFF(e, k) (((e) << 8) + (((((k) >> 3) ^ ((e) & 7)) << 3) + ((k) & 7)))
// generic-K variant (row stride KT cols); KT power of two >= 64
#define HK(e, k, KT) ((e) * (KT) + (((((k) >> 3) ^ ((e) & 7)) << 3) + ((k) & 7)))

// ---------------- weight prep (+ degree histogram in blockIdx.y==13) ----------------
struct TD { const float* s; unsigned short* d; int R, C, r0, ld; };
struct TDs { TD t[13]; };

// ld==0: vectorized cast copy. ld!=0: coalesced 32x32 LDS-tile transpose
__global__ void wprep(TDs all, const int* __restrict__ dstI, int* __restrict__ deg) {
  __shared__ float tile[32][33];
  if (blockIdx.y == 13) {   // degree histogram (independent of weight prep)
    int stride = gridDim.x * blockDim.x;
    for (int e = blockIdx.x * blockDim.x + threadIdx.x; e < NE; e += stride)
      atomicAdd(&deg[dstI[e]], 1);
    return;
  }
  TD td = all.t[blockIdx.y];
  if (td.ld == 0) {                       // vector cast copy (R multiple of 8)
    int stride = gridDim.x * blockDim.x;
    int n8 = td.R >> 3;
    for (int i = blockIdx.x * blockDim.x + threadIdx.x; i < n8; i += stride) {
      const float* s = td.s + (size_t)i * 8;
      float4 lo = *(const float4*)s;
      float4 hi = *(const float4*)(s + 4);
      uint4 o = make_uint4(cvt_pk_bf16(lo.x, lo.y), cvt_pk_bf16(lo.z, lo.w),
                           cvt_pk_bf16(hi.x, hi.y), cvt_pk_bf16(hi.z, hi.w));
      *(uint4*)(td.d + (size_t)i * 8) = o;
    }
    return;
  }
  // transpose: dst[c*R + r] = src[(r0+r)*ld + c]; R,C multiples of 32
  int tilesR = td.R >> 5, tilesC = td.C >> 5;
  int nt = tilesR * tilesC;
  int tr = threadIdx.x >> 5, tc = threadIdx.x & 31;
  for (int tIdx = blockIdx.x; tIdx < nt; tIdx += gridDim.x) {
    int t_r = tIdx / tilesC, t_c = tIdx - t_r * tilesC;
    __syncthreads();   // previous iteration's reads done
#pragma unroll
    for (int rr = 0; rr < 4; ++rr) {
      int r = t_r * 32 + tr + rr * 8;
      tile[tr + rr * 8][tc] = td.s[(size_t)(td.r0 + r) * td.ld + t_c * 32 + tc];
    }
    __syncthreads();
#pragma unroll
    for (int rr = 0; rr < 4; ++rr) {
      int c = t_c * 32 + tr + rr * 8;
      td.d[(size_t)c * td.R + t_r * 32 + tc] = f2bf(tile[tc][tr + rr * 8]);
    }
  }
}

// block 0: exclusive scan of deg; blocks 1..79: batch bounds; block 80: bias concat vectors
__global__ void scan_bounds(const int* __restrict__ deg, int* __restrict__ rowstart,
                            int* __restrict__ cursor, const int* __restrict__ batch,
                            int* __restrict__ bstart,
                            const float* __restrict__ g1b1, const float* __restrict__ g2b1,
                            float* __restrict__ b1cat1, float* __restrict__ b1cat2) {
  if (blockIdx.x == 0) {
    __shared__ int part[256];
    int t = threadIdx.x;
    int c0 = t * 80; if (c0 > NN) c0 = NN;
    int c1 = c0 + 80; if (c1 > NN) c1 = NN;
    int s = 0;
    for (int i = c0; i < c1; ++i) s += deg[i];
    part[t] = s;
    __syncthreads();
    if (t == 0) {
      int run = 0;
      for (int i = 0; i < 256; ++i) { int v = part[i]; part[i] = run; run += v; }
    }
    __syncthreads();
    int run = part[t];
    for (int i = c0; i < c1; ++i) { rowstart[i] = run; cursor[i] = run; run += deg[i]; }
    if (t == 255) rowstart[NN] = run;   // == NE
  } else if (blockIdx.x == 80) {
    int t = threadIdx.x;
    b1cat1[t] = g1b1[t]; b1cat1[256 + t] = 0.f;
    b1cat2[t] = g2b1[t]; b1cat2[256 + t] = 0.f;
  } else {
    int n = (blockIdx.x - 1) * 256 + threadIdx.x;
    if (n >= NN) return;
    int bn = batch[n];
    if (n == 0) {
      for (int b2 = 0; b2 <= bn; ++b2) bstart[b2] = 0;
    } else {
      int bp = batch[n - 1];
      for (int b2 = bp + 1; b2 <= bn; ++b2) bstart[b2] = n;
    }
    if (n == NN - 1) {
      for (int b2 = bn + 1; b2 <= NBATCH; ++b2) bstart[b2] = NN;
    }
  }
}

__global__ void fillcsr(const int* __restrict__ srcI, const int* __restrict__ dstI,
                        int* __restrict__ cursor, int* __restrict__ sSrc,
                        int* __restrict__ sDst) {
  int e = blockIdx.x * 256 + threadIdx.x;
  if (e < NE) {
    int d = dstI[e];
    int slot = atomicAdd(&cursor[d], 1);
    sDst[slot] = d;
    sSrc[slot] = srcI[e];
  }
}

// ---------------- transposed-weight GEMM with LDS-staged input rows ----------------
// Out[r][f] = In[r][:] . WT[f][:] + bias; In rows staged once (kills 4x wf-redundant reads)
template <int KT>
__global__ __launch_bounds__(512, 2) void gemmTs(
    const unsigned short* __restrict__ WT, const unsigned short* __restrict__ In,
    const float* __restrict__ bias, unsigned short* __restrict__ Out,
    int M, int Nout, int ldo) {
  __shared__ __align__(16) unsigned short h[128 * KT];
  const int tid = threadIdx.x;
  const int rb0 = blockIdx.y * 128;
  {  // stage 128 In rows, coalesced
    int r = tid & 127;
    int rg = rb0 + r; if (rg >= M) rg = M - 1;
    const unsigned short* src = In + (size_t)rg * KT + (tid >> 7) * (KT / 4);
    int c0 = (tid >> 7) * (KT / 4);
#pragma unroll
    for (int i = 0; i < KT / 32; ++i) {
      short8 v = *(const short8*)(src + i * 8);
      *(short8*)&h[HK(r, c0 + i * 8, KT)] = v;
    }
  }
  __syncthreads();

  const int lane = tid & 63, w = tid >> 6;
  const int wf = w >> 1, we = w & 1;
  const int l15 = lane & 15, q = lane >> 4;
  const int fb = blockIdx.x * 256 + wf * 64;
  const int rb = rb0 + we * 64;
  f32x4 acc[4][4] = {};
  const short8 zz = {0, 0, 0, 0, 0, 0, 0, 0};
  for (int kc = 0; kc < KT; kc += 32) {
    short8 a[4], bq[4];
#pragma unroll
    for (int i = 0; i < 4; ++i) {
      if (fb + i * 16 < Nout)
        a[i] = *(const short8*)(WT + (size_t)(fb + i * 16 + l15) * KT + kc + q * 8);
      else
        a[i] = zz;
      bq[i] = *(const short8*)&h[HK(we * 64 + i * 16 + l15, kc + q * 8, KT)];
    }
#pragma unroll
    for (int i = 0; i < 4; ++i)
#pragma unroll
      for (int j = 0; j < 4; ++j)
        acc[i][j] = __builtin_amdgcn_mfma_f32_16x16x32_bf16(a[i], bq[j], acc[i][j], 0, 0, 0);
  }
#pragma unroll
  for (int i = 0; i < 4; ++i) {
    int f0 = fb + i * 16 + q * 4;
    if (f0 >= Nout) continue;
    float4 bs = make_float4(0.f, 0.f, 0.f, 0.f);
    if (bias) bs = *(const float4*)(bias + f0);
#pragma unroll
    for (int j = 0; j < 4; ++j) {
      int r = rb + j * 16 + l15;
      if (r >= M) continue;
      uint2 o = make_uint2(cvt_pk_bf16(acc[i][j][0] + bs.x, acc[i][j][1] + bs.y),
                           cvt_pk_bf16(acc[i][j][2] + bs.z, acc[i][j][3] + bs.w));
      *(uint2*)(Out + (size_t)r * ldo + f0) = o;
    }
  }
}

// ---------------- fused per-edge MLP (128-edge tiles) + dst-segmented h2 aggregation ----------------
// h1 = relu(PQ[sDst][0:256] + PQ[sSrc][256:512])  (b1 pre-folded into PQ dst half via gemm bias)
// h2 = relu(h1 @ W2 + b2); segmented dst-run sum of h2 -> agg  (W3/b3 applied per-NODE later)
// Bijective XCD swizzle (m204): each XCD owns a contiguous tile chunk -> contiguous PQ[dst]
// rows (~2.5MB) become L2-resident instead of scattering across 8 XCD L2s.
__global__ __launch_bounds__(512, 2) void edge_h2agg(
    const unsigned short* __restrict__ PQ, const int* __restrict__ sSrc,
    const int* __restrict__ sDst,
    const unsigned short* __restrict__ W2T, const float* __restrict__ b2,
    float* __restrict__ agg) {
  __shared__ __align__(16) unsigned short h[128 * 256];  // 64 KB -> 2 blocks/CU
  __shared__ int seg_s[129];                             // [128]=count, [0..]=starts
  const int tid = threadIdx.x;
  // NTILE=2500, 8 XCDs: q=312, r=4. xcd<r gets 313 tiles, else 312. Bijective.
  const int orig = blockIdx.x;
  const int xcd = orig & 7;
  const int base = orig >> 3;
  const int tb = (xcd < 4 ? xcd * 313 : 4 * 313 + (xcd - 4) * 312) + base;
  const int e0 = tb * 128;
  if (tid == 0) seg_s[128] = 0;

  {  // phase 0: gather + h1 (4 threads per edge, 64 cols each)
    int r = tid & 127;
    int c0 = (tid >> 7) * 64;
    int dn = sDst[e0 + r];
    int sn = sSrc[e0 + r];
    const unsigned short* pd = PQ + (size_t)dn * 512 + c0;
    const unsigned short* ps = PQ + (size_t)sn * 512 + 256 + c0;
#pragma unroll
    for (int i = 0; i < 8; ++i) {
      short8 dv = *(const short8*)(pd + i * 8);
      short8 sv = *(const short8*)(ps + i * 8);
      float a0 = fmaxf(bf2fs(dv[0]) + bf2fs(sv[0]), 0.f);
      float a1 = fmaxf(bf2fs(dv[1]) + bf2fs(sv[1]), 0.f);
      float a2 = fmaxf(bf2fs(dv[2]) + bf2fs(sv[2]), 0.f);
      float a3 = fmaxf(bf2fs(dv[3]) + bf2fs(sv[3]), 0.f);
      float a4 = fmaxf(bf2fs(dv[4]) + bf2fs(sv[4]), 0.f);
      float a5 = fmaxf(bf2fs(dv[5]) + bf2fs(sv[5]), 0.f);
      float a6 = fmaxf(bf2fs(dv[6]) + bf2fs(sv[6]), 0.f);
      float a7 = fmaxf(bf2fs(dv[7]) + bf2fs(sv[7]), 0.f);
      uint4 o = make_uint4(cvt_pk_bf16(a0, a1), cvt_pk_bf16(a2, a3),
                           cvt_pk_bf16(a4, a5), cvt_pk_bf16(a6, a7));
      *(uint4*)&h[HOFF(r, c0 + i * 8)] = o;
    }
  }
  __syncthreads();

  const int lane = tid & 63, w = tid >> 6;
  const int wf = w >> 1, we = w & 1;
  const int l15 = lane & 15, q = lane >> 4;
  const int fb = wf * 64, eb = we * 64;
  f32x4 acc[4][4];

  // ---- GEMM: h2^T = W2T @ h1^T ----
#pragma unroll
  for (int i = 0; i < 4; ++i)
#pragma unroll
    for (int j = 0; j < 4; ++j) { f32x4 z = {0.f, 0.f, 0.f, 0.f}; acc[i][j] = z; }
  for (int kc = 0; kc < 256; kc += 32) {
    short8 a[4], bq[4];
#pragma unroll
    for (int i = 0; i < 4; ++i)
      a[i] = *(const short8*)(W2T + (size_t)(fb + i * 16 + l15) * 256 + kc + q * 8);
#pragma unroll
    for (int j = 0; j < 4; ++j)
      bq[j] = *(const short8*)&h[HOFF(eb + j * 16 + l15, kc + q * 8)];
#pragma unroll
    for (int i = 0; i < 4; ++i)
#pragma unroll
      for (int j = 0; j < 4; ++j)
        acc[i][j] = __builtin_amdgcn_mfma_f32_16x16x32_bf16(a[i], bq[j], acc[i][j], 0, 0, 0);
  }
  __syncthreads();  // all reads of h1 done
#pragma unroll
  for (int i = 0; i < 4; ++i) {
    int f0 = fb + i * 16 + q * 4;
    float4 bs = *(const float4*)(b2 + f0);
#pragma unroll
    for (int j = 0; j < 4; ++j) {
      int e = eb + j * 16 + l15;
      float v0 = fmaxf(acc[i][j][0] + bs.x, 0.f);
      float v1 = fmaxf(acc[i][j][1] + bs.y, 0.f);
      float v2 = fmaxf(acc[i][j][2] + bs.z, 0.f);
      float v3 = fmaxf(acc[i][j][3] + bs.w, 0.f);
      uint2 o = make_uint2(cvt_pk_bf16(v0, v1), cvt_pk_bf16(v2, v3));
      *(uint2*)&h[HOFF(e, f0)] = o;  // h2
    }
  }
  if (tid < 128) {
    int d0 = sDst[e0 + tid];
    bool flag = (tid == 0) || (sDst[e0 + tid - 1] != d0);
    if (flag) {
      int idx = atomicAdd(&seg_s[128], 1);
      seg_s[idx] = tid;
    }
  }
  __syncthreads();

  // segmented reduction of h2: 8 groups x 64 lanes (4 feats/lane), fp32
  {
    int cnt = seg_s[128];
    int f4 = (tid & 63) * 4;
    int sg = tid >> 6;
    for (int k = sg; k < cnt; k += 8) {
      int start = seg_s[k];
      int end = 128;
      for (int j2 = 0; j2 < cnt; ++j2) {
        int v = seg_s[j2];
        if (v > start && v < end) end = v;
      }
      int node = sDst[e0 + start];
      float s0 = 0.f, s1 = 0.f, s2 = 0.f, s3 = 0.f;
      for (int rr = start; rr < end; ++rr) {
        ushort4 v = *(const ushort4*)&h[HOFF(rr, f4)];
        s0 += bf2f(v.x); s1 += bf2f(v.y); s2 += bf2f(v.z); s3 += bf2f(v.w);
      }
      float* pr = agg + (size_t)node * 256 + f4;
      if (start == 0 || end == 128) {  // run may continue in neighbor tile
        atomicAdd(pr + 0, s0); atomicAdd(pr + 1, s1);
        atomicAdd(pr + 2, s2); atomicAdd(pr + 3, s3);
      } else {                         // wholly inside this tile: unique owner
        *(float4*)pr = make_float4(s0, s1, s2, s3);
      }
    }
  }
}

// ---------------- per-node GEMM fused with relu+LN: out = LN(relu(agg@W3 + deg*b3)) -------------
__global__ __launch_bounds__(512, 2) void node_gemm_ln(
    const unsigned short* __restrict__ W3T, const float* __restrict__ aggH2,
    const float* __restrict__ b3, const int* __restrict__ deg,
    const float* __restrict__ lng, const float* __restrict__ lnb,
    unsigned short* __restrict__ out) {
  __shared__ __align__(16) unsigned short h[128 * 256];  // 64 KB
  __shared__ float rstat[256];   // [0..127]=sum, [128..255]=sumsq per local row
  const int tid = threadIdx.x;
  const int rb0 = blockIdx.x * 128;
  if (tid < 256) rstat[tid] = 0.f;
  {  // stage 128 rows, convert fp32 -> bf16 once
    int r = tid & 127;
    int rg = rb0 + r; if (rg >= NN) rg = NN - 1;
    int c0 = (tid >> 7) * 64;
    const float* src = aggH2 + (size_t)rg * 256 + c0;
#pragma unroll
    for (int i = 0; i < 8; ++i) {
      float4 lo = *(const float4*)(src + i * 8);
      float4 hi = *(const float4*)(src + i * 8 + 4);
      uint4 o = make_uint4(cvt_pk_bf16(lo.x, lo.y), cvt_pk_bf16(lo.z, lo.w),
                           cvt_pk_bf16(hi.x, hi.y), cvt_pk_bf16(hi.z, hi.w));
      *(uint4*)&h[HOFF(r, c0 + i * 8)] = o;
    }
  }
  __syncthreads();

  const int lane = tid & 63, w = tid >> 6;
  const int wf = w >> 1, we = w & 1;
  const int l15 = lane & 15, q = lane >> 4;
  const int fb = wf * 64;                      // 256 feats per block via 4 wave-pairs
  const int rb = rb0 + we * 64;                // 128 rows per block via 2 halves
  f32x4 acc[4][4] = {};
  for (int kc = 0; kc < 256; kc += 32) {
    short8 a[4], bq[4];
#pragma unroll
    for (int i = 0; i < 4; ++i) {
      a[i] = *(const short8*)(W3T + (size_t)(fb + i * 16 + l15) * 256 + kc + q * 8);
      bq[i] = *(const short8*)&h[HOFF(we * 64 + i * 16 + l15, kc + q * 8)];
    }
#pragma unroll
    for (int i = 0; i < 4; ++i)
#pragma unroll
      for (int j = 0; j < 4; ++j)
        acc[i][j] = __builtin_amdgcn_mfma_f32_16x16x32_bf16(a[i], bq[j], acc[i][j], 0, 0, 0);
  }

  // per-row deg and bias fragments
  float dgj[4];
#pragma unroll
  for (int j = 0; j < 4; ++j) {
    int rr = rb + j * 16 + l15;
    dgj[j] = (float)deg[rr < NN ? rr : NN - 1];
  }
  f32x4 bsv[4];
#pragma unroll
  for (int i = 0; i < 4; ++i)
    bsv[i] = *(const f32x4*)(b3 + fb + i * 16 + q * 4);

  // pass 1: stats.  v = relu(acc + dg*b3); reduce 64 feats via shfl over q-lanes,
  // then LDS atomicAdd across the 4 wf wave-pairs.
#pragma unroll
  for (int j = 0; j < 4; ++j) {
    float s = 0.f, sq = 0.f;
#pragma unroll
    for (int i = 0; i < 4; ++i)
#pragma unroll
      for (int r = 0; r < 4; ++r) {
        float v = fmaxf(acc[i][j][r] + dgj[j] * bsv[i][r], 0.f);
        s += v; sq += v * v;
      }
    s += __shfl_xor(s, 16); s += __shfl_xor(s, 32);
    sq += __shfl_xor(sq, 16); sq += __shfl_xor(sq, 32);
    if (q == 0) {
      int lr = we * 64 + j * 16 + l15;
      atomicAdd(&rstat[lr], s);
      atomicAdd(&rstat[128 + lr], sq);
    }
  }
  __syncthreads();

  // pass 2: normalize from live accumulators, write bf16
#pragma unroll
  for (int j = 0; j < 4; ++j) {
    int lr = we * 64 + j * 16 + l15;
    int rr = rb + j * 16 + l15;
    float mu = rstat[lr] * (1.f / 256.f);
    float var = rstat[128 + lr] * (1.f / 256.f) - mu * mu;
    float rs = rsqrtf(var + 1e-5f);
    if (rr < NN) {
#pragma unroll
      for (int i = 0; i < 4; ++i) {
        int f0 = fb + i * 16 + q * 4;
        f32x4 gg = *(const f32x4*)(lng + f0);
        f32x4 bb = *(const f32x4*)(lnb + f0);
        float o0 = (fmaxf(acc[i][j][0] + dgj[j] * bsv[i][0], 0.f) - mu) * rs * gg[0] + bb[0];
        float o1 = (fmaxf(acc[i][j][1] + dgj[j] * bsv[i][1], 0.f) - mu) * rs * gg[1] + bb[1];
        float o2 = (fmaxf(acc[i][j][2] + dgj[j] * bsv[i][2], 0.f) - mu) * rs * gg[2] + bb[2];
        float o3 = (fmaxf(acc[i][j][3] + dgj[j] * bsv[i][3], 0.f) - mu) * rs * gg[3] + bb[3];
        *(uint2*)(out + (size_t)rr * 256 + f0) =
            make_uint2(cvt_pk_bf16(o0, o1), cvt_pk_bf16(o2, o3));
      }
    }
  }
}

// ---------------- fused assignment MLP + gumbel softmax (64 node-rows per block) ----------------
__global__ __launch_bounds__(512, 4) void assign_gumbel(
    const unsigned short* __restrict__ x2b, const unsigned short* __restrict__ aw1T,
    const float* __restrict__ ab1, const unsigned short* __restrict__ aw2T,
    const float* __restrict__ ab2, const float* __restrict__ u,
    float* __restrict__ sf, float* __restrict__ entacc, float* __restrict__ avgacc) {
  __shared__ __align__(16) unsigned short sh[64 * 256];   // 32 KB
  __shared__ float sh_logit[64 * 33];
  __shared__ float lavg[32];
  __shared__ float lent;
  const int tid = threadIdx.x;
  const int n0 = blockIdx.x * 64;
  if (tid < 32) lavg[tid] = 0.f;
  if (tid == 0) lent = 0.f;

  const int lane = tid & 63, w = tid >> 6;
  const int l15 = lane & 15, q = lane >> 4;

  {  // phase A: assh tile
    const int wf = w >> 1, we = w & 1;
    const int fb = wf * 64, eb = we * 32;
    f32x4 acc[4][2];
#pragma unroll
    for (int i = 0; i < 4; ++i)
#pragma unroll
      for (int j = 0; j < 2; ++j) { f32x4 z = {0.f, 0.f, 0.f, 0.f}; acc[i][j] = z; }
    for (int kc = 0; kc < 256; kc += 32) {
      short8 a[4], bq[2];
#pragma unroll
      for (int i = 0; i < 4; ++i)
        a[i] = *(const short8*)(aw1T + (size_t)(fb + i * 16 + l15) * 256 + kc + q * 8);
#pragma unroll
      for (int j = 0; j < 2; ++j) {
        int rr = n0 + eb + j * 16 + l15;
        if (rr >= NN) rr = NN - 1;
        bq[j] = *(const short8*)(x2b + (size_t)rr * 256 + kc + q * 8);
      }
#pragma unroll
      for (int i = 0; i < 4; ++i)
#pragma unroll
        for (int j = 0; j < 2; ++j)
          acc[i][j] = __builtin_amdgcn_mfma_f32_16x16x32_bf16(a[i], bq[j], acc[i][j], 0, 0, 0);
    }
#pragma unroll
    for (int i = 0; i < 4; ++i) {
      int f0 = fb + i * 16 + q * 4;
      float4 bs = *(const float4*)(ab1 + f0);
#pragma unroll
      for (int j = 0; j < 2; ++j) {
        int e = eb + j * 16 + l15;
        ushort4 o;
        o.x = f2bf(fmaxf(acc[i][j][0] + bs.x, 0.f));
        o.y = f2bf(fmaxf(acc[i][j][1] + bs.y, 0.f));
        o.z = f2bf(fmaxf(acc[i][j][2] + bs.z, 0.f));
        o.w = f2bf(fmaxf(acc[i][j][3] + bs.w, 0.f));
        *(ushort4*)&sh[HOFF(e, f0)] = o;
      }
    }
  }
  __syncthreads();

  {  // phase B: logits (N=32). wave w: row-group rg=w&3, feat-group fg=w>>2 (fg<2)
    const int rg = w & 3, fg = w >> 2;
    if (fg < 2) {
      f32x4 acc = {0.f, 0.f, 0.f, 0.f};
      for (int kc = 0; kc < 256; kc += 32) {
        short8 a = *(const short8*)(aw2T + (size_t)(fg * 16 + l15) * 256 + kc + q * 8);
        short8 bq = *(const short8*)&sh[HOFF(rg * 16 + l15, kc + q * 8)];
        acc = __builtin_amdgcn_mfma_f32_16x16x32_bf16(a, bq, acc, 0, 0, 0);
      }
      int rowL = rg * 16 + l15;
#pragma unroll
      for (int t2 = 0; t2 < 4; ++t2) {
        int f = fg * 16 + q * 4 + t2;
        sh_logit[rowL * 33 + f] = acc[t2] + ab2[f];
      }
    }
  }
  __syncthreads();

  // phase C: gumbel softmax, 4 threads per row (8 slots each)
  if (tid < 256) {
    int rowL = tid >> 2, sub = tid & 3;
    int n = n0 + rowL;
    if (n < NN) {
      int j0 = sub * 8;
      float z[8];
      float4 u0 = *(const float4*)(u + (size_t)n * 32 + j0);
      float4 u1 = *(const float4*)(u + (size_t)n * 32 + j0 + 4);
      float uu[8] = {u0.x, u0.y, u0.z, u0.w, u1.x, u1.y, u1.z, u1.w};
      float m = -1e30f;
#pragma unroll
      for (int j = 0; j < 8; ++j) {
        z[j] = sh_logit[rowL * 33 + j0 + j] - logf(-logf(uu[j] + 1e-9f) + 1e-9f);
        m = fmaxf(m, z[j]);
      }
      m = fmaxf(m, __shfl_xor(m, 1));
      m = fmaxf(m, __shfl_xor(m, 2));
      float sum = 0.f;
#pragma unroll
      for (int j = 0; j < 8; ++j) { z[j] = expf(z[j] - m); sum += z[j]; }
      sum += __shfl_xor(sum, 1);
      sum += __shfl_xor(sum, 2);
      float inv = 1.f / sum;
      float ent = 0.f;
      float so[8];
#pragma unroll
      for (int j = 0; j < 8; ++j) {
        float sj = z[j] * inv;
        so[j] = sj;
        ent += sj * logf(sj + 1e-9f);
        atomicAdd(&lavg[j0 + j], sj);
      }
      *(float4*)(sf + (size_t)n * 32 + j0) = make_float4(so[0], so[1], so[2], so[3]);
      *(float4*)(sf + (size_t)n * 32 + j0 + 4) = make_float4(so[4], so[5], so[6], so[7]);
      ent += __shfl_xor(ent, 1);
      ent += __shfl_xor(ent, 2);
      if (sub == 0) atomicAdd(&lent, ent);
    }
  }
  __syncthreads();
  if (tid < 32) atomicAdd(&avgacc[tid], lavg[tid]);
  if (tid == 0) atomicAdd(entacc, lent);
}

// ---------------- pooling stage 1: per-(batch, chunk-set) partials, atomic-free ----------------
__global__ __launch_bounds__(512, 4) void pool_part(
    const unsigned short* __restrict__ x2b, const float* __restrict__ sf,
    const int* __restrict__ bstart, float* __restrict__ part) {
  const int b = blockIdx.x, ci = blockIdx.y;
  const int n0b = bstart[b], n1b = bstart[b + 1];
  const int t = threadIdx.x;
  const int si = t >> 4;            // 0..31
  const int h0 = (t & 15) * 16;     // 0..240
  float acc[16];
#pragma unroll
  for (int k = 0; k < 16; ++k) acc[k] = 0.f;
  for (int nst = n0b + ci * 64; nst < n1b; nst += 16 * 64) {
    int nend = (nst + 64 < n1b) ? nst + 64 : n1b;
    for (int n = nst; n < nend; ++n) {
      float sv = sf[(size_t)n * 32 + si];
      const unsigned short* xr = x2b + (size_t)n * 256 + h0;
      short8 x0 = *(const short8*)xr;
      short8 x1 = *(const short8*)(xr + 8);
#pragma unroll
      for (int j = 0; j < 8; ++j) acc[j] = fmaf(sv, bf2fs(x0[j]), acc[j]);
#pragma unroll
      for (int j = 0; j < 8; ++j) acc[8 + j] = fmaf(sv, bf2fs(x1[j]), acc[8 + j]);
    }
  }
  float* pp = part + (((size_t)b * 16 + ci) << 13) + si * 256 + h0;
#pragma unroll
  for (int k = 0; k < 16; k += 4)
    *(float4*)(pp + k) = make_float4(acc[k], acc[k + 1], acc[k + 2], acc[k + 3]);
}

// ---------------- pooling stage 2: pooled[b][si][h] = sum_ci part[b][ci][si][h] ----------------
__global__ void pool_reduce(const float* __restrict__ part, float* __restrict__ pooled) {
  int g = blockIdx.x * 256 + threadIdx.x;   // 512 blocks x 256 = 131072 outputs
  int b = g >> 13, rem = g & 8191;
  const float* p = part + (((size_t)b * 16) << 13) + rem;
  float s = 0.f;
#pragma unroll
  for (int c = 0; c < 16; ++c) s += p[(size_t)c << 13];
  pooled[g] = s;
}

// ---------------- fused output MLP (+ loss in block 0): latent = relu(pooled@ow1+ob1)@ow2+ob2 ----
__global__ __launch_bounds__(512, 4) void out_mlp(
    const float* __restrict__ pooled, const unsigned short* __restrict__ ow1T,
    const float* __restrict__ ob1, const unsigned short* __restrict__ ow2T,
    const float* __restrict__ ob2, float* __restrict__ latent,
    const float* __restrict__ accs, float* __restrict__ outloss) {
  __shared__ __align__(16) unsigned short sh[64 * 256];   // hid tile, 32 KB
  const int tid = threadIdx.x;
  const int n0 = blockIdx.x * 64;
  const int lane = tid & 63, w = tid >> 6;
  const int l15 = lane & 15, q = lane >> 4;

  if (blockIdx.x == 0 && tid < 64) {  // loss (accs ready: assign_gumbel completed earlier)
    float d = 0.f;
    if (tid < 32) {
      float a = accs[16 + tid] * (1.f / NN);
      d = a * logf(a + 1e-9f);
    }
    for (int off = 32; off >= 1; off >>= 1) d += __shfl_xor(d, off);
    if (tid == 0) outloss[0] = -accs[0] * (1.f / NN) + d;
  }

  {  // phase A: hid = relu(pooled @ ow1 + ob1), pooled converted inline to bf16
    const int wf = w >> 1, we = w & 1;
    const int fb = wf * 64, eb = we * 32;
    f32x4 acc[4][2];
#pragma unroll
    for (int i = 0; i < 4; ++i)
#pragma unroll
      for (int j = 0; j < 2; ++j) { f32x4 z = {0.f, 0.f, 0.f, 0.f}; acc[i][j] = z; }
    for (int kc = 0; kc < 256; kc += 32) {
      short8 a[4], bq[2];
#pragma unroll
      for (int i = 0; i < 4; ++i)
        a[i] = *(const short8*)(ow1T + (size_t)(fb + i * 16 + l15) * 256 + kc + q * 8);
#pragma unroll
      for (int j = 0; j < 2; ++j) {
        int rr = n0 + eb + j * 16 + l15;
        const float* pr = pooled + (size_t)rr * 256 + kc + q * 8;
        float4 lo = *(const float4*)pr;
        float4 hi = *(const float4*)(pr + 4);
        short8 o;
        o[0] = (short)f2bf(lo.x); o[1] = (short)f2bf(lo.y);
        o[2] = (short)f2bf(lo.z); o[3] = (short)f2bf(lo.w);
        o[4] = (short)f2bf(hi.x); o[5] = (short)f2bf(hi.y);
        o[6] = (short)f2bf(hi.z); o[7] = (short)f2bf(hi.w);
        bq[j] = o;
      }
#pragma unroll
      for (int i = 0; i < 4; ++i)
#pragma unroll
        for (int j = 0; j < 2; ++j)
          acc[i][j] = __builtin_amdgcn_mfma_f32_16x16x32_bf16(a[i], bq[j], acc[i][j], 0, 0, 0);
    }
#pragma unroll
    for (int i = 0; i < 4; ++i) {
      int f0 = fb + i * 16 + q * 4;
      float4 bs = *(const float4*)(ob1 + f0);
#pragma unroll
      for (int j = 0; j < 2; ++j) {
        int e = eb + j * 16 + l15;
        ushort4 o;
        o.x = f2bf(fmaxf(acc[i][j][0] + bs.x, 0.f));
        o.y = f2bf(fmaxf(acc[i][j][1] + bs.y, 0.f));
        o.z = f2bf(fmaxf(acc[i][j][2] + bs.z, 0.f));
        o.w = f2bf(fmaxf(acc[i][j][3] + bs.w, 0.f));
        *(ushort4*)&sh[HOFF(e, f0)] = o;
      }
    }
  }
  __syncthreads();

  {  // phase B: latent = hid @ ow2 + ob2 (Nout=128)
    const int wf = w >> 1, we = w & 1;
    const int fb = wf * 32, eb = we * 32;
    f32x4 acc[2][2];
#pragma unroll
    for (int i = 0; i < 2; ++i)
#pragma unroll
      for (int j = 0; j < 2; ++j) { f32x4 z = {0.f, 0.f, 0.f, 0.f}; acc[i][j] = z; }
    for (int kc = 0; kc < 256; kc += 32) {
      short8 a[2], bq[2];
#pragma unroll
      for (int i = 0; i < 2; ++i)
        a[i] = *(const short8*)(ow2T + (size_t)(fb + i * 16 + l15) * 256 + kc + q * 8);
#pragma unroll
      for (int j = 0; j < 2; ++j)
        bq[j] = *(const short8*)&sh[HOFF(eb + j * 16 + l15, kc + q * 8)];
#pragma unroll
      for (int i = 0; i < 2; ++i)
#pragma unroll
        for (int j = 0; j < 2; ++j)
          acc[i][j] = __builtin_amdgcn_mfma_f32_16x16x32_bf16(a[i], bq[j], acc[i][j], 0, 0, 0);
    }
#pragma unroll
    for (int i = 0; i < 2; ++i) {
      int f0 = fb + i * 16 + q * 4;
      float4 bs = *(const float4*)(ob2 + f0);
#pragma unroll
      for (int j = 0; j < 2; ++j) {
        int rr = n0 + eb + j * 16 + l15;
        *(float4*)(latent + (size_t)rr * 128 + f0) =
            make_float4(acc[i][j][0] + bs.x, acc[i][j][1] + bs.y,
                        acc[i][j][2] + bs.z, acc[i][j][3] + bs.w);
      }
    }
  }
}

// ---------------- orchestration ----------------
extern "C" void kernel_launch(void* const* d_in, const int* in_sizes, int n_in,
                              void* d_out, int out_size, void* d_ws, size_t ws_size,
                              hipStream_t stream) {
  (void)in_sizes; (void)n_in; (void)out_size; (void)ws_size;
  const float* x = (const float*)d_in[0];
  const float* u = (const float*)d_in[1];
  const int* ei = (const int*)d_in[2];
  const int* batch = (const int*)d_in[3];
  const float* g1w1 = (const float*)d_in[4];
  const float* g1b1 = (const float*)d_in[5];
  const float* g1w2 = (const float*)d_in[6];
  const float* g1b2 = (const float*)d_in[7];
  const float* g1w3 = (const float*)d_in[8];
  const float* g1b3 = (const float*)d_in[9];
  const float* ln1g = (const float*)d_in[10];
  const float* ln1b = (const float*)d_in[11];
  const float* g2w1 = (const float*)d_in[12];
  const float* g2b1 = (const float*)d_in[13];
  const float* g2w2 = (const float*)d_in[14];
  const float* g2b2 = (const float*)d_in[15];
  const float* g2w3 = (const float*)d_in[16];
  const float* g2b3 = (const float*)d_in[17];
  const float* ln2g = (const float*)d_in[18];
  const float* ln2b = (const float*)d_in[19];
  const float* aw1 = (const float*)d_in[20];
  const float* ab1 = (const float*)d_in[21];
  const float* aw2 = (const float*)d_in[22];
  const float* ab2 = (const float*)d_in[23];
  const float* ow1 = (const float*)d_in[24];
  const float* ob1 = (const float*)d_in[25];
  const float* ow2 = (const float*)d_in[26];
  const float* ob2 = (const float*)d_in[27];
  const int* srcI = ei;        // edge_index[0] = src
  const int* dstI = ei + NE;   // edge_index[1] = dst

  char* wp = (char*)d_ws;
  size_t off = 0;
  auto alloc = [&](size_t bytes) {
    void* p = wp + off;
    off += (bytes + 255) & ~(size_t)255;
    return p;
  };
  unsigned short* W1catT = (unsigned short*)alloc((size_t)512 * 64 * 2);
  unsigned short* W2catT = (unsigned short*)alloc((size_t)512 * 256 * 2);
  unsigned short* g1w2T = (unsigned short*)alloc((size_t)256 * 256 * 2);
  unsigned short* g1w3T = (unsigned short*)alloc((size_t)256 * 256 * 2);
  unsigned short* g2w2T = (unsigned short*)alloc((size_t)256 * 256 * 2);
  unsigned short* g2w3T = (unsigned short*)alloc((size_t)256 * 256 * 2);
  unsigned short* aw1T = (unsigned short*)alloc((size_t)256 * 256 * 2);
  unsigned short* aw2T = (unsigned short*)alloc((size_t)32 * 256 * 2);
  unsigned short* ow1T = (unsigned short*)alloc((size_t)256 * 256 * 2);
  unsigned short* ow2T = (unsigned short*)alloc((size_t)128 * 256 * 2);
  unsigned short* xb = (unsigned short*)alloc((size_t)NN * 64 * 2);
  unsigned short* PQ = (unsigned short*)alloc((size_t)NN * 512 * 2);
  unsigned short* x1b = (unsigned short*)alloc((size_t)NN * 256 * 2);
  unsigned short* x2b = (unsigned short*)alloc((size_t)NN * 256 * 2);
  int* bstart = (int*)alloc(32 * 4);
  int* cursor = (int*)alloc((size_t)NN * 4);
  int* rowstart = (int*)alloc((size_t)(NN + 1) * 4);
  int* sSrc = (int*)alloc((size_t)NE * 4);
  int* sDst = (int*)alloc((size_t)NE * 4);
  float* b1cat1 = (float*)alloc(512 * 4);
  float* b1cat2 = (float*)alloc(512 * 4);
  // ---- contiguous zero-init region (single memset) ----
  char* zbase = (char*)(wp + off);
  float* accs = (float*)alloc(64 * 4);
  float* pooled = (float*)alloc((size_t)512 * 256 * 4);
  int* deg = (int*)alloc((size_t)NN * 4);
  float* agg1 = (float*)alloc((size_t)NN * 256 * 4);
  float* agg2 = (float*)alloc((size_t)NN * 256 * 4);
  size_t zbytes = (size_t)((char*)(wp + off) - zbase);

  // pool partials (16*16*8192 fp32 = 8.4 MB) reuse agg1: agg1 is dead after layer-1 node_gemm_ln.
  float* poolpart = agg1;

  float* out_f = (float*)d_out;
  float* out_latent = out_f;                 // [16*32*128] = 65536
  float* out_s = out_f + 65536;              // [20000*32]
  float* out_loss = out_f + 65536 + 640000;  // [1]

  TDs tds;
  tds.t[0] = {g1w1, W1catT, 64, 256, 0, 256};
  tds.t[1] = {g1w1, W1catT + 256 * 64, 64, 256, 64, 256};
  tds.t[2] = {g1w2, g1w2T, 256, 256, 0, 256};
  tds.t[3] = {g1w3, g1w3T, 256, 256, 0, 256};
  tds.t[4] = {g2w1, W2catT, 256, 256, 0, 256};
  tds.t[5] = {g2w1, W2catT + 256 * 256, 256, 256, 256, 256};
  tds.t[6] = {g2w2, g2w2T, 256, 256, 0, 256};
  tds.t[7] = {g2w3, g2w3T, 256, 256, 0, 256};
  tds.t[8] = {aw1, aw1T, 256, 256, 0, 256};
  tds.t[9] = {aw2, aw2T, 256, 32, 0, 32};
  tds.t[10] = {ow1, ow1T, 256, 256, 0, 256};
  tds.t[11] = {ow2, ow2T, 256, 128, 0, 128};
  tds.t[12] = {x, xb, NN * 64, 1, 0, 0};

  (void)hipMemsetAsync(zbase, 0, zbytes, stream);   // accs+pooled+deg+agg1+agg2
  // weight prep + degree histogram in one dispatch (y==13 -> hist)
  wprep<<<dim3(128, 14), 256, 0, stream>>>(tds, dstI, deg);

  // CSR scan + batch bounds + bias concat, then permutation fill
  scan_bounds<<<dim3(81), 256, 0, stream>>>(deg, rowstart, cursor, batch, bstart,
                                            g1b1, g2b1, b1cat1, b1cat2);
  fillcsr<<<dim3(1250), 256, 0, stream>>>(srcI, dstI, cursor, sSrc, sDst);

  // layer 1 (b1 folded into PQ dst half; W3+b3+relu+LN fused into node_gemm_ln)
  gemmTs<64><<<dim3(2, 157), 512, 0, stream>>>(W1catT, xb, b1cat1, PQ, NN, 512, 512);
  edge_h2agg<<<dim3(NTILE), 512, 0, stream>>>(PQ, sSrc, sDst, g1w2T, g1b2, agg1);
  node_gemm_ln<<<dim3(157), 512, 0, stream>>>(g1w3T, agg1, g1b3, deg, ln1g, ln1b, x1b);

  // layer 2
  gemmTs<256><<<dim3(2, 157), 512, 0, stream>>>(W2catT, x1b, b1cat2, PQ, NN, 512, 512);
  edge_h2agg<<<dim3(NTILE), 512, 0, stream>>>(PQ, sSrc, sDst, g2w2T, g2b2, agg2);
  node_gemm_ln<<<dim3(157), 512, 0, stream>>>(g2w3T, agg2, g2b3, deg, ln2g, ln2b, x2b);

  // fused assignment MLP + gumbel softmax (s fp32 to d_out)
  assign_gumbel<<<dim3(313), 512, 0, stream>>>(x2b, aw1T, ab1, aw2T, ab2, u,
                                               out_s, accs, accs + 16);

  // pooling: atomic-free two-stage (partials reuse agg1, dead after layer-1 node_gemm_ln)
  pool_part<<<dim3(16, 16), 512, 0, stream>>>(x2b, out_s, bstart, poolpart);
  pool_reduce<<<dim3(512), 256, 0, stream>>>(poolpart, pooled);

  // fused output MLP (+loss)
  out_mlp<<<dim3(8), 512, 0, stream>>>(pooled, ow1T, ob1, ow2T, ob2, out_latent,
                                       accs, out_loss);
}